// Round 11
// baseline (252.379 us; speedup 1.0000x reference)
//
#include <hip/hip_runtime.h>

#define KVSZ 288            // per-cloud: 256 kv[h][d][e] + 32 ksum[feat]
#define EPS_LN 1e-5f
#define EPS_Z  1e-6f
#define BS 512              // block size (8 waves); halves per-block staging cost,
                            // raises k_mid occupancy ceiling 37.5% -> 50%

typedef __attribute__((ext_vector_type(8))) short bf16x8;   // MFMA A/B frag (4 VGPR)
typedef __attribute__((ext_vector_type(4))) float f32x4;    // MFMA C/D frag

#define MFMA(a, b, c) __builtin_amdgcn_mfma_f32_16x16x32_bf16(a, b, c, 0, 0, 0)

// packed-weight offsets (ushort units) inside pw / inside staged LDS
#define PWE 0                       // embed matrix [32k][32n], identity k-order
#define LBASE(l) (1024 + (l) * 8192)
#define PQ 0
#define PO 1024
#define P1 2048
#define P2 4096
#define PK 6144
#define PV 7168

__device__ __forceinline__ unsigned short f2bf(float f) {   // fp32 -> bf16 RNE
  union { float f; unsigned u; } x; x.f = f;
  unsigned r = x.u + 0x7fff + ((x.u >> 16) & 1);
  return (unsigned short)(r >> 16);
}

__device__ __forceinline__ unsigned pkbf(float a, float b) {
#if __has_builtin(__builtin_amdgcn_cvt_pk_bf16_f32)
  typedef __attribute__((ext_vector_type(2))) __bf16 bf16x2_t;
  bf16x2_t v = __builtin_amdgcn_cvt_pk_bf16_f32(a, b);
  return __builtin_bit_cast(unsigned, v);
#else
  return (unsigned)f2bf(a) | ((unsigned)f2bf(b) << 16);
#endif
}

__device__ __forceinline__ float bfu(unsigned short s) {    // bf16 -> fp32
  union { float f; unsigned u; } x; x.u = ((unsigned)s) << 16; return x.f;
}

__device__ __forceinline__ void lds_fence() { asm volatile("s_waitcnt lgkmcnt(0)" ::: "memory"); }
__device__ __forceinline__ float phi(float x) { return x > 0.f ? x + 1.f : __expf(x); }

// Feature-major dataflow: D'[out_feat][point] = W^T (A-frag) @ h^T (B-frag).
// B-frag k-order: lane-group q, slot j -> feature (j>=4)*16 + 4q + (j&3).
// D-frag regs {hc0[r]=feat 4q+r, hc1[r]=feat 16+4q+r} pack in-lane (cvt_pk)
// into the next B operand: no LDS transposes on the h path.
__device__ __forceinline__ int perm32(int kp) {
  return ((kp & 4) << 2) | (((kp >> 3) << 2) + (kp & 3));
}

__device__ __forceinline__ bf16x8 bbuild(f32x4 lo, f32x4 hi) {
  union { bf16x8 v; unsigned u[4]; } cv;
  cv.u[0] = pkbf(lo[0], lo[1]); cv.u[1] = pkbf(lo[2], lo[3]);
  cv.u[2] = pkbf(hi[0], hi[1]); cv.u[3] = pkbf(hi[2], hi[3]);
  return cv.v;
}

// ---- weight packing (k_prep, grid-stride): dst[n*32+kp] = W[perm32(kp)][n] ----
__device__ __forceinline__ void stage_a32(unsigned short* dst, const float* __restrict__ W,
                                          int N, int gt, int gs) {
  for (int i = gt; i < 32 * N; i += gs) {
    int n = i >> 5, kp = i & 31;
    dst[i] = f2bf(W[perm32(kp) * N + n]);
  }
}
__device__ __forceinline__ void stage_a64(unsigned short* dst, const float* __restrict__ W,
                                          int gt, int gs) {
  for (int i = gt; i < 64 * 32; i += gs) {
    int n = i >> 6, kp = i & 63;
    int kl = ((kp >> 5) << 5) + perm32(kp & 31);
    dst[i] = f2bf(W[kl * 32 + n]);
  }
}

// cooperative kvm build into LDS: A[e][kp] = same-head ? kv[h][d][e] : 0, d=perm32(kp)
__device__ __forceinline__ void stage_kvm_lds(unsigned short* dst,
                                              const float* __restrict__ kvg, int tid) {
  for (int i = tid; i < 1024; i += BS) {
    int e = i >> 5, kp = i & 31;
    int d = perm32(kp);
    float v = ((d >> 3) == (e >> 3)) ? kvg[(e >> 3) * 64 + (d & 7) * 8 + (e & 7)] : 0.f;
    dst[i] = f2bf(v);
  }
}

// LayerNorm over 32 features, feature-major: in-lane over 8 regs + xor16/xor32.
__device__ __forceinline__ void ln_t(f32x4& a0, f32x4& a1, float4 g0, float4 g1,
                                     float4 b0, float4 b1) {
  float s = a0[0] + a0[1] + a0[2] + a0[3] + a1[0] + a1[1] + a1[2] + a1[3];
  s += __shfl_xor(s, 16); s += __shfl_xor(s, 32);
  float mu = s * (1.f / 32.f);
  float vv = 0.f;
#pragma unroll
  for (int r = 0; r < 4; r++) {
    a0[r] -= mu; a1[r] -= mu;
    vv += a0[r] * a0[r] + a1[r] * a1[r];
  }
  vv += __shfl_xor(vv, 16); vv += __shfl_xor(vv, 32);
  float rstd = rsqrtf(vv * (1.f / 32.f) + EPS_LN);
  a0[0] = a0[0] * rstd * g0.x + b0.x; a0[1] = a0[1] * rstd * g0.y + b0.y;
  a0[2] = a0[2] * rstd * g0.z + b0.z; a0[3] = a0[3] * rstd * g0.w + b0.w;
  a1[0] = a1[0] * rstd * g1.x + b1.x; a1[1] = a1[1] * rstd * g1.y + b1.y;
  a1[2] = a1[2] * rstd * g1.z + b1.z; a1[3] = a1[3] * rstd * g1.w + b1.w;
}

// attention + FFN for one layer; weights from LDS (lw: Q/O/W1/W2 at
// 0/1024/2048/4096), kvm+ksum from LDS; phase A consumes the PRELOADED
// B-frags hBp (bit-identical to bbuild(hc) — cvt_pk of exact bf16 is identity).
__device__ __forceinline__ void layer_core_l(
    f32x4 (&hc0)[4], f32x4 (&hc1)[4], const bf16x8 (&hBp)[4],
    const unsigned short* lw, const unsigned short* kvm, const float* kss,
    int quad, int m,
    const float* __restrict__ bq, const float* __restrict__ bo,
    const float* __restrict__ g1, const float* __restrict__ be1,
    const float* __restrict__ bf1, const float* __restrict__ bf2,
    const float* __restrict__ g2, const float* __restrict__ be2) {
  const int k0 = quad * 8, q4 = quad * 4;
  // ---- phase A: q = phi(h@wq+bq); attn = (q@kvmat)*z; h = LN1(h + attn@wo+bo)
  {
    const bf16x8 wqA0 = *(const bf16x8*)(lw + PQ + m * 32 + k0);
    const bf16x8 wqA1 = *(const bf16x8*)(lw + PQ + (16 + m) * 32 + k0);
    const bf16x8 woA0 = *(const bf16x8*)(lw + PO + m * 32 + k0);
    const bf16x8 woA1 = *(const bf16x8*)(lw + PO + (16 + m) * 32 + k0);
    const bf16x8 kvA0 = *(const bf16x8*)(kvm + m * 32 + k0);
    const bf16x8 kvA1 = *(const bf16x8*)(kvm + (16 + m) * 32 + k0);
    const float4 bq0 = *(const float4*)(bq + q4), bq1 = *(const float4*)(bq + 16 + q4);
    const float4 bo0 = *(const float4*)(bo + q4), bo1 = *(const float4*)(bo + 16 + q4);
    const float4 g10 = *(const float4*)(g1 + q4), g11 = *(const float4*)(g1 + 16 + q4);
    const float4 e10 = *(const float4*)(be1 + q4), e11 = *(const float4*)(be1 + 16 + q4);
    const float4 ks0 = *(const float4*)(kss + q4);
    const float4 ks1 = *(const float4*)(kss + 16 + q4);
#pragma unroll
    for (int mt = 0; mt < 4; mt++) {
      f32x4 q0 = {bq0.x, bq0.y, bq0.z, bq0.w};
      f32x4 q1 = {bq1.x, bq1.y, bq1.z, bq1.w};
      q0 = MFMA(wqA0, hBp[mt], q0);
      q1 = MFMA(wqA1, hBp[mt], q1);
#pragma unroll
      for (int r = 0; r < 4; r++) { q0[r] = phi(q0[r]); q1[r] = phi(q1[r]); }
      bf16x8 qB = bbuild(q0, q1);
      f32x4 zz = {0.f, 0.f, 0.f, 0.f};
      f32x4 at0 = MFMA(kvA0, qB, zz);
      f32x4 at1 = MFMA(kvA1, qB, zz);
      // z: per-head (8-feat) q.ksum; groups q and q^1 hold the two 4-feat halves
      float p0 = q0[0] * ks0.x + q0[1] * ks0.y + q0[2] * ks0.z + q0[3] * ks0.w;
      float p1 = q1[0] * ks1.x + q1[1] * ks1.y + q1[2] * ks1.z + q1[3] * ks1.w;
      p0 += __shfl_xor(p0, 16);
      p1 += __shfl_xor(p1, 16);
      float z0 = 1.f / (p0 + EPS_Z), z1 = 1.f / (p1 + EPS_Z);
      bf16x8 aB;
      {
        union { bf16x8 v; unsigned u[4]; } cv;
        cv.u[0] = pkbf(at0[0] * z0, at0[1] * z0); cv.u[1] = pkbf(at0[2] * z0, at0[3] * z0);
        cv.u[2] = pkbf(at1[0] * z1, at1[1] * z1); cv.u[3] = pkbf(at1[2] * z1, at1[3] * z1);
        aB = cv.v;
      }
      f32x4 h0 = hc0[mt], h1 = hc1[mt];
      h0[0] += bo0.x; h0[1] += bo0.y; h0[2] += bo0.z; h0[3] += bo0.w;
      h1[0] += bo1.x; h1[1] += bo1.y; h1[2] += bo1.z; h1[3] += bo1.w;
      h0 = MFMA(woA0, aB, h0);
      h1 = MFMA(woA1, aB, h1);
      ln_t(h0, h1, g10, g11, e10, e11);
      hc0[mt] = h0; hc1[mt] = h1;
    }
  }
  // ---- phase B: h = LN2(h + relu(h@w1+b1)@w2+b2)
  {
    bf16x8 w1A[4]; float4 b1f[4];
#pragma unroll
    for (int nt = 0; nt < 4; nt++) {
      w1A[nt] = *(const bf16x8*)(lw + P1 + (nt * 16 + m) * 32 + k0);
      b1f[nt] = *(const float4*)(bf1 + nt * 16 + q4);
    }
    const bf16x8 w2L0 = *(const bf16x8*)(lw + P2 + m * 64 + k0);
    const bf16x8 w2H0 = *(const bf16x8*)(lw + P2 + m * 64 + 32 + k0);
    const bf16x8 w2L1 = *(const bf16x8*)(lw + P2 + (16 + m) * 64 + k0);
    const bf16x8 w2H1 = *(const bf16x8*)(lw + P2 + (16 + m) * 64 + 32 + k0);
    const float4 b20 = *(const float4*)(bf2 + q4), b21 = *(const float4*)(bf2 + 16 + q4);
    const float4 g20 = *(const float4*)(g2 + q4), g21 = *(const float4*)(g2 + 16 + q4);
    const float4 e20 = *(const float4*)(be2 + q4), e21 = *(const float4*)(be2 + 16 + q4);
#pragma unroll
    for (int mt = 0; mt < 4; mt++) {
      bf16x8 hB = bbuild(hc0[mt], hc1[mt]);
      f32x4 hd[4];
#pragma unroll
      for (int nt = 0; nt < 4; nt++) {
        f32x4 ini = {b1f[nt].x, b1f[nt].y, b1f[nt].z, b1f[nt].w};
        hd[nt] = MFMA(w1A[nt], hB, ini);
#pragma unroll
        for (int r = 0; r < 4; r++) hd[nt][r] = fmaxf(hd[nt][r], 0.f);
      }
      bf16x8 fL = bbuild(hd[0], hd[1]);
      bf16x8 fH = bbuild(hd[2], hd[3]);
      f32x4 o0 = hc0[mt], o1 = hc1[mt];
      o0[0] += b20.x; o0[1] += b20.y; o0[2] += b20.z; o0[3] += b20.w;
      o1[0] += b21.x; o1[1] += b21.y; o1[2] += b21.z; o1[3] += b21.w;
      o0 = MFMA(w2L0, fL, o0);
      o0 = MFMA(w2H0, fH, o0);
      o1 = MFMA(w2L1, fL, o1);
      o1 = MFMA(w2H1, fH, o1);
      ln_t(o0, o1, g20, g21, e20, e21);
      hc0[mt] = o0; hc1[mt] = o1;
    }
  }
}

// kn = phi(h@wk+bk), vn = h@wv+bv from PRELOADED B-frags; kv += kn^T-outer-vn
// via one LDS transpose per 32-point chunk (points are the contraction dim).
__device__ __forceinline__ void kv_stage_l(
    const bf16x8 (&hBp)[4], unsigned short* tw,
    const unsigned short* lwK, const unsigned short* lwV,
    float* blk, int quad, int m,
    const float* __restrict__ bk, const float* __restrict__ bv) {
  const int k0 = quad * 8, q4 = quad * 4;
  unsigned short* Tk = tw;           // [32 feat][40] bf16
  unsigned short* Tv = tw + 1280;    // [32 feat][40] bf16
  const bf16x8 wkA0 = *(const bf16x8*)(lwK + m * 32 + k0);
  const bf16x8 wkA1 = *(const bf16x8*)(lwK + (16 + m) * 32 + k0);
  const bf16x8 wvA0 = *(const bf16x8*)(lwV + m * 32 + k0);
  const bf16x8 wvA1 = *(const bf16x8*)(lwV + (16 + m) * 32 + k0);
  const float4 bk0 = *(const float4*)(bk + q4), bk1 = *(const float4*)(bk + 16 + q4);
  const float4 bv0 = *(const float4*)(bv + q4), bv1 = *(const float4*)(bv + 16 + q4);
  f32x4 accA = {0.f, 0.f, 0.f, 0.f}, accB = {0.f, 0.f, 0.f, 0.f};
  f32x4 ksa0 = {0.f, 0.f, 0.f, 0.f}, ksa1 = {0.f, 0.f, 0.f, 0.f};
#pragma unroll
  for (int ch = 0; ch < 2; ch++) {
#pragma unroll
    for (int mtl = 0; mtl < 2; mtl++) {
      int mt = ch * 2 + mtl;
      f32x4 kn0 = {bk0.x, bk0.y, bk0.z, bk0.w};
      f32x4 kn1 = {bk1.x, bk1.y, bk1.z, bk1.w};
      f32x4 vn0 = {bv0.x, bv0.y, bv0.z, bv0.w};
      f32x4 vn1 = {bv1.x, bv1.y, bv1.z, bv1.w};
      kn0 = MFMA(wkA0, hBp[mt], kn0);
      kn1 = MFMA(wkA1, hBp[mt], kn1);
      vn0 = MFMA(wvA0, hBp[mt], vn0);
      vn1 = MFMA(wvA1, hBp[mt], vn1);
      int cb = mtl * 16 + m;
#pragma unroll
      for (int r = 0; r < 4; r++) {
        kn0[r] = phi(kn0[r]); kn1[r] = phi(kn1[r]);
        ksa0[r] += kn0[r];    ksa1[r] += kn1[r];
        Tk[(q4 + r) * 40 + cb]      = f2bf(kn0[r]);
        Tk[(16 + q4 + r) * 40 + cb] = f2bf(kn1[r]);
        Tv[(q4 + r) * 40 + cb]      = f2bf(vn0[r]);
        Tv[(16 + q4 + r) * 40 + cb] = f2bf(vn1[r]);
      }
    }
    lds_fence();
    bf16x8 akL = *(const bf16x8*)(Tk + m * 40 + k0);
    bf16x8 akH = *(const bf16x8*)(Tk + (16 + m) * 40 + k0);
    bf16x8 avL = *(const bf16x8*)(Tv + m * 40 + k0);
    bf16x8 avH = *(const bf16x8*)(Tv + (16 + m) * 40 + k0);
    accA = MFMA(akL, avL, accA);   // d,e in 0..15  (heads 0,1 diag blocks)
    accB = MFMA(akH, avH, accB);   // d,e in 16..31 (heads 2,3 diag blocks)
    lds_fence();
  }
  // ksum[feat]: reduce over the 16 point-lanes
#pragma unroll
  for (int r = 0; r < 4; r++) {
    float v0 = ksa0[r], v1 = ksa1[r];
    v0 += __shfl_xor(v0, 1); v0 += __shfl_xor(v0, 2); v0 += __shfl_xor(v0, 4); v0 += __shfl_xor(v0, 8);
    v1 += __shfl_xor(v1, 1); v1 += __shfl_xor(v1, 2); v1 += __shfl_xor(v1, 4); v1 += __shfl_xor(v1, 8);
    if (m == 0) {
      atomicAdd(&blk[256 + q4 + r], v0);
      atomicAdd(&blk[272 + q4 + r], v1);
    }
  }
  if ((quad >> 1) == (m >> 3)) {   // same-head diagonal blocks only
    int h0 = quad >> 1, h1 = 2 + (quad >> 1), e = m & 7;
#pragma unroll
    for (int r = 0; r < 4; r++) {
      int d = (q4 + r) & 7;
      atomicAdd(&blk[h0 * 64 + d * 8 + e], accA[r]);
      atomicAdd(&blk[h1 * 64 + d * 8 + e], accB[r]);
    }
  }
}

// K0 (64 blocks, grid-stride): pack weights into frag-ready layout + zero kv.
__global__ __launch_bounds__(256) void k_prep(
    const float* __restrict__ w_in, const float* __restrict__ w_pos,
    const float* __restrict__ wq, const float* __restrict__ wk,
    const float* __restrict__ wv, const float* __restrict__ wo,
    const float* __restrict__ w1, const float* __restrict__ w2,
    unsigned short* __restrict__ pw, float* __restrict__ kvbuf) {
  const int gt = blockIdx.x * 256 + threadIdx.x;
  const int gs = gridDim.x * 256;
  for (int i = gt; i < 2 * 16 * KVSZ; i += gs) kvbuf[i] = 0.f;
  for (int i = gt; i < 1024; i += gs) {         // wE identity k-order: cin|pos|0
    int n = i >> 5, k = i & 31;
    float v = k < 16 ? w_in[k * 32 + n] : (k < 19 ? w_pos[(k - 16) * 32 + n] : 0.f);
    pw[PWE + i] = f2bf(v);
  }
  for (int l = 0; l < 2; l++) {
    unsigned short* b = pw + LBASE(l);
    stage_a32(b + PQ, wq + l * 1024, 32, gt, gs);
    stage_a32(b + PO, wo + l * 1024, 32, gt, gs);
    stage_a32(b + P1, w1 + l * 2048, 64, gt, gs);
    stage_a64(b + P2, w2 + l * 2048, gt, gs);
    stage_a32(b + PK, wk + l * 1024, 32, gt, gs);
    stage_a32(b + PV, wv + l * 1024, 32, gt, gs);
  }
}

// K1: embed -> h0 (bf16 B-frag layout in hb, or f32 in hf), layer-0 kv accum.
// x/pos loads issued before LDS staging (T14).
template <int H16>
__global__ __launch_bounds__(BS) void k_embed(
    const float* __restrict__ x, const float* __restrict__ pos,
    const float* __restrict__ b_in, const float* __restrict__ b_pos,
    const float* __restrict__ bk, const float* __restrict__ bv,
    const unsigned short* __restrict__ pw, unsigned short* __restrict__ hb,
    float* __restrict__ hf, float* __restrict__ gkv) {
  __shared__ __align__(16) unsigned short lws[3072];
  __shared__ __align__(16) unsigned short tiles[(BS / 64) * 2560];
  __shared__ float blk[KVSZ];
  const int tid = threadIdx.x;
  const int wv_ = tid >> 6, lane = tid & 63, quad = lane >> 4, m = lane & 15;
  unsigned short* tw = tiles + wv_ * 2560;
  const int cloud = blockIdx.x >> 6;            // 1024 blocks / 16 clouds
  const int wbase = blockIdx.x * BS + wv_ * 64;
  const int k0 = quad * 8, q4 = quad * 4;
  // ---- issue x/pos loads early
  float4 xt0[4], xt1[4];
  float pp0[4], pp1[4], pp2[4];
#pragma unroll
  for (int mt = 0; mt < 4; mt++) {
    int p = wbase + mt * 16 + m;
    if (quad < 2) {
      const float4* xp = (const float4*)(x + (size_t)p * 16 + quad * 8);
      xt0[mt] = xp[0]; xt1[mt] = xp[1];
    } else if (quad == 2) {
      const float* pq = pos + (size_t)p * 3;
      pp0[mt] = pq[0]; pp1[mt] = pq[1]; pp2[mt] = pq[2];
    }
  }
  // ---- stage weights (overlaps with x/pos loads in flight)
  for (int j = tid; j < 384; j += BS) {
    int i = j * 8;
    const unsigned short* src = (i < 1024) ? (pw + PWE + i)
                                           : (pw + LBASE(0) + PK + (i - 1024));
    *(bf16x8*)(lws + i) = *(const bf16x8*)src;
  }
  for (int i = tid; i < KVSZ; i += BS) blk[i] = 0.f;
  __syncthreads();
  const bf16x8 weA0 = *(const bf16x8*)(lws + m * 32 + k0);
  const bf16x8 weA1 = *(const bf16x8*)(lws + (16 + m) * 32 + k0);
  float4 bi0, bi1;
  {
    float4 a = *(const float4*)(b_in + q4), b = *(const float4*)(b_pos + q4);
    bi0 = make_float4(a.x + b.x, a.y + b.y, a.z + b.z, a.w + b.w);
    float4 c = *(const float4*)(b_in + 16 + q4), d = *(const float4*)(b_pos + 16 + q4);
    bi1 = make_float4(c.x + d.x, c.y + d.y, c.z + d.z, c.w + d.w);
  }
  bf16x8 fr[4];
#pragma unroll
  for (int mt = 0; mt < 4; mt++) {
    int p = wbase + mt * 16 + m;
    union { bf16x8 v; unsigned u[4]; } xb;
    xb.u[0] = xb.u[1] = xb.u[2] = xb.u[3] = 0;
    if (quad < 2) {
      xb.u[0] = pkbf(xt0[mt].x, xt0[mt].y); xb.u[1] = pkbf(xt0[mt].z, xt0[mt].w);
      xb.u[2] = pkbf(xt1[mt].x, xt1[mt].y); xb.u[3] = pkbf(xt1[mt].z, xt1[mt].w);
    } else if (quad == 2) {
      xb.u[0] = pkbf(pp0[mt], pp1[mt]); xb.u[1] = pkbf(pp2[mt], 0.f);
    }
    f32x4 i0 = {bi0.x, bi0.y, bi0.z, bi0.w};
    f32x4 i1 = {bi1.x, bi1.y, bi1.z, bi1.w};
    f32x4 h0 = MFMA(weA0, xb.v, i0);
    f32x4 h1 = MFMA(weA1, xb.v, i1);
    fr[mt] = bbuild(h0, h1);
    if (H16) {
      *(bf16x8*)(hb + ((size_t)p * 32 + quad * 8)) = fr[mt];
    } else {
      float* hp = hf + (size_t)p * 32;
      *(float4*)(hp + q4)      = make_float4(h0[0], h0[1], h0[2], h0[3]);
      *(float4*)(hp + 16 + q4) = make_float4(h1[0], h1[1], h1[2], h1[3]);
    }
  }
  kv_stage_l(fr, tw, lws + 1024, lws + 2048, blk, quad, m, bk, bv);
  __syncthreads();
  float* g = gkv + cloud * KVSZ;
  for (int i = tid; i < KVSZ; i += BS) atomicAdd(&g[i], blk[i]);
}

// K2: layer-0 attn+FFN (in place on h), layer-1 kn/vn -> kv accum.
// hb frag loads issued before LDS staging.
template <int H16>
__global__ __launch_bounds__(BS) void k_mid(
    const float* __restrict__ bq, const float* __restrict__ bo,
    const float* __restrict__ g1, const float* __restrict__ be1,
    const float* __restrict__ bf1, const float* __restrict__ bf2,
    const float* __restrict__ g2, const float* __restrict__ be2,
    const float* __restrict__ bkn, const float* __restrict__ bvn,
    const unsigned short* __restrict__ pw, const float* __restrict__ kv_in,
    float* __restrict__ gkv_out, unsigned short* __restrict__ hb,
    float* __restrict__ hf) {
  __shared__ __align__(16) unsigned short lws[8192];
  __shared__ __align__(16) unsigned short kvm[1024];
  __shared__ __align__(16) float kss[32];
  __shared__ __align__(16) unsigned short tiles[(BS / 64) * 2560];
  __shared__ float blk[KVSZ];
  const int tid = threadIdx.x;
  const int wv_ = tid >> 6, lane = tid & 63, quad = lane >> 4, m = lane & 15;
  unsigned short* tw = tiles + wv_ * 2560;
  const int cloud = blockIdx.x >> 6;
  const int wbase = blockIdx.x * BS + wv_ * 64;
  const int q4 = quad * 4;
  const float* kvg = kv_in + cloud * KVSZ;
  // ---- issue h loads early
  bf16x8 fr[4];
  if (H16) {
#pragma unroll
    for (int mt = 0; mt < 4; mt++) {
      int p = wbase + mt * 16 + m;
      fr[mt] = *(const bf16x8*)(hb + ((size_t)p * 32 + quad * 8));
    }
  }
  // ---- stage weights + kvm + ksum (h loads in flight)
  for (int j = tid; j < 1024; j += BS) {
    int i = j * 8;
    const unsigned short* src = (i < 6144) ? (pw + LBASE(0) + i)
                                           : (pw + LBASE(1) + PK + (i - 6144));
    *(bf16x8*)(lws + i) = *(const bf16x8*)src;
  }
  stage_kvm_lds(kvm, kvg, tid);
  if (tid < 32) kss[tid] = kvg[256 + tid];
  for (int i = tid; i < KVSZ; i += BS) blk[i] = 0.f;
  __syncthreads();
  f32x4 hc0[4], hc1[4];
#pragma unroll
  for (int mt = 0; mt < 4; mt++) {
    if (H16) {
#pragma unroll
      for (int r = 0; r < 4; r++) {
        hc0[mt][r] = bfu((unsigned short)fr[mt][r]);
        hc1[mt][r] = bfu((unsigned short)fr[mt][4 + r]);
      }
    } else {
      int p = wbase + mt * 16 + m;
      const float* hp = hf + (size_t)p * 32;
      float4 lo = *(const float4*)(hp + q4);
      float4 hi = *(const float4*)(hp + 16 + q4);
      hc0[mt][0] = lo.x; hc0[mt][1] = lo.y; hc0[mt][2] = lo.z; hc0[mt][3] = lo.w;
      hc1[mt][0] = hi.x; hc1[mt][1] = hi.y; hc1[mt][2] = hi.z; hc1[mt][3] = hi.w;
      fr[mt] = bbuild(hc0[mt], hc1[mt]);
    }
  }
  layer_core_l(hc0, hc1, fr, lws, kvm, kss, quad, m,
               bq, bo, g1, be1, bf1, bf2, g2, be2);
#pragma unroll
  for (int mt = 0; mt < 4; mt++) {
    int p = wbase + mt * 16 + m;
    fr[mt] = bbuild(hc0[mt], hc1[mt]);
    if (H16) {
      *(bf16x8*)(hb + ((size_t)p * 32 + quad * 8)) = fr[mt];
    } else {
      float* hp = hf + (size_t)p * 32;
      *(float4*)(hp + q4)      = make_float4(hc0[mt][0], hc0[mt][1], hc0[mt][2], hc0[mt][3]);
      *(float4*)(hp + 16 + q4) = make_float4(hc1[mt][0], hc1[mt][1], hc1[mt][2], hc1[mt][3]);
    }
  }
  kv_stage_l(fr, tw, lws + 6144, lws + 7168, blk, quad, m, bkn, bvn);
  __syncthreads();
  float* g = gkv_out + cloud * KVSZ;
  for (int i = tid; i < KVSZ; i += BS) atomicAdd(&g[i], blk[i]);
}

// K3: layer-1 attn+FFN -> final fp32 output. Early hb loads, same pattern.
template <int H16>
__global__ __launch_bounds__(BS) void k_last(
    const float* __restrict__ bq, const float* __restrict__ bo,
    const float* __restrict__ g1, const float* __restrict__ be1,
    const float* __restrict__ bf1, const float* __restrict__ bf2,
    const float* __restrict__ g2, const float* __restrict__ be2,
    const unsigned short* __restrict__ pw, const float* __restrict__ kv_in,
    const unsigned short* __restrict__ hb, float* __restrict__ out) {
  __shared__ __align__(16) unsigned short lws[6144];
  __shared__ __align__(16) unsigned short kvm[1024];
  __shared__ __align__(16) float kss[32];
  const int tid = threadIdx.x;
  const int wv_ = tid >> 6, lane = tid & 63, quad = lane >> 4, m = lane & 15;
  const int cloud = blockIdx.x >> 6;
  const int wbase = blockIdx.x * BS + wv_ * 64;
  const int q4 = quad * 4;
  const float* kvg = kv_in + cloud * KVSZ;
  bf16x8 fr[4];
  if (H16) {
#pragma unroll
    for (int mt = 0; mt < 4; mt++) {
      int p = wbase + mt * 16 + m;
      fr[mt] = *(const bf16x8*)(hb + ((size_t)p * 32 + quad * 8));
    }
  }
  for (int j = tid; j < 768; j += BS)
    *(bf16x8*)(lws + j * 8) = *(const bf16x8*)(pw + LBASE(1) + j * 8);
  stage_kvm_lds(kvm, kvg, tid);
  if (tid < 32) kss[tid] = kvg[256 + tid];
  __syncthreads();
  f32x4 hc0[4], hc1[4];
#pragma unroll
  for (int mt = 0; mt < 4; mt++) {
    if (H16) {
#pragma unroll
      for (int r = 0; r < 4; r++) {
        hc0[mt][r] = bfu((unsigned short)fr[mt][r]);
        hc1[mt][r] = bfu((unsigned short)fr[mt][4 + r]);
      }
    } else {
      int p = wbase + mt * 16 + m;
      const float* hp = out + (size_t)p * 32;
      float4 lo = *(const float4*)(hp + q4);
      float4 hi = *(const float4*)(hp + 16 + q4);
      hc0[mt][0] = lo.x; hc0[mt][1] = lo.y; hc0[mt][2] = lo.z; hc0[mt][3] = lo.w;
      hc1[mt][0] = hi.x; hc1[mt][1] = hi.y; hc1[mt][2] = hi.z; hc1[mt][3] = hi.w;
      fr[mt] = bbuild(hc0[mt], hc1[mt]);
    }
  }
  layer_core_l(hc0, hc1, fr, lws, kvm, kss, quad, m,
               bq, bo, g1, be1, bf1, bf2, g2, be2);
#pragma unroll
  for (int mt = 0; mt < 4; mt++) {
    int p = wbase + mt * 16 + m;
    float* hp = out + (size_t)p * 32;
    *(float4*)(hp + q4)      = make_float4(hc0[mt][0], hc0[mt][1], hc0[mt][2], hc0[mt][3]);
    *(float4*)(hp + 16 + q4) = make_float4(hc1[mt][0], hc1[mt][1], hc1[mt][2], hc1[mt][3]);
  }
}

extern "C" void kernel_launch(void* const* d_in, const int* in_sizes, int n_in,
                              void* d_out, int out_size, void* d_ws, size_t ws_size,
                              hipStream_t stream) {
  (void)in_sizes; (void)n_in; (void)out_size;
  const float* x     = (const float*)d_in[0];
  const float* pos   = (const float*)d_in[1];
  // d_in[2] = batch (arange // N_PER): identity mapping, unused
  const float* w_in  = (const float*)d_in[3];
  const float* b_in  = (const float*)d_in[4];
  const float* w_pos = (const float*)d_in[5];
  const float* b_pos = (const float*)d_in[6];
  const float* wq  = (const float*)d_in[7];
  const float* bq  = (const float*)d_in[8];
  const float* wk  = (const float*)d_in[9];
  const float* bk  = (const float*)d_in[10];
  const float* wv  = (const float*)d_in[11];
  const float* bv  = (const float*)d_in[12];
  const float* wo  = (const float*)d_in[13];
  const float* bo  = (const float*)d_in[14];
  const float* g1  = (const float*)d_in[15];
  const float* be1 = (const float*)d_in[16];
  const float* w1  = (const float*)d_in[17];
  const float* bf1 = (const float*)d_in[18];
  const float* w2  = (const float*)d_in[19];
  const float* bf2 = (const float*)d_in[20];
  const float* g2  = (const float*)d_in[21];
  const float* be2 = (const float*)d_in[22];
  float* out = (float*)d_out;
  // workspace layout: [0,36864) kv (2 layers x 16 clouds x 288 f32);
  // [40960, 75776) packed weights (17408 bf16); [131072, +33.5MB) bf16 h.
  float* kvbuf = (float*)d_ws;
  unsigned short* pw = (unsigned short*)((char*)d_ws + 40960);
  unsigned short* hb = (unsigned short*)((char*)d_ws + 131072);
  const size_t need = 131072ull + 524288ull * 32ull * 2ull;
  const bool h16 = ws_size >= need;

  k_prep<<<dim3(64), dim3(256), 0, stream>>>(w_in, w_pos, wq, wk, wv, wo, w1, w2,
                                             pw, kvbuf);
  dim3 grid(524288 / BS), block(BS);
  if (h16) {
    k_embed<1><<<grid, block, 0, stream>>>(x, pos, b_in, b_pos, bk, bv, pw, hb, out, kvbuf);
    k_mid<1><<<grid, block, 0, stream>>>(bq, bo, g1, be1, bf1, bf2, g2, be2,
                                         bk + 32, bv + 32, pw, kvbuf,
                                         kvbuf + 16 * KVSZ, hb, out);
    k_last<1><<<grid, block, 0, stream>>>(bq + 32, bo + 32, g1 + 32, be1 + 32,
                                          bf1 + 64, bf2 + 32, g2 + 32, be2 + 32,
                                          pw, kvbuf + 16 * KVSZ, hb, out);
  } else {
    k_embed<0><<<grid, block, 0, stream>>>(x, pos, b_in, b_pos, bk, bv, pw, hb, out, kvbuf);
    k_mid<0><<<grid, block, 0, stream>>>(bq, bo, g1, be1, bf1, bf2, g2, be2,
                                         bk + 32, bv + 32, pw, kvbuf,
                                         kvbuf + 16 * KVSZ, hb, out);
    k_last<0><<<grid, block, 0, stream>>>(bq + 32, bo + 32, g1 + 32, be1 + 32,
                                          bf1 + 64, bf2 + 32, g2 + 32, be2 + 32,
                                          pw, kvbuf + 16 * KVSZ, hb, out);
  }
}

// Round 12
// 247.213 us; speedup vs baseline: 1.0209x; 1.0209x over previous
//
#include <hip/hip_runtime.h>

#define KVSZ 288            // per-cloud: 256 kv[h][d][e] + 32 ksum[feat]
#define EPS_LN 1e-5f
#define EPS_Z  1e-6f
#define BS 256              // block size (4 waves) — round-11 A/B: 512 regressed
#define NB 2048             // grid blocks; 128 blocks per cloud

typedef __attribute__((ext_vector_type(8))) short bf16x8;   // MFMA A/B frag (4 VGPR)
typedef __attribute__((ext_vector_type(4))) float f32x4;    // MFMA C/D frag

#define MFMA(a, b, c) __builtin_amdgcn_mfma_f32_16x16x32_bf16(a, b, c, 0, 0, 0)

// packed-weight offsets (ushort units) inside pw / inside staged LDS
#define PWE 0                       // embed matrix [32k][32n], identity k-order
#define LBASE(l) (1024 + (l) * 8192)
#define PQ 0
#define PO 1024
#define P1 2048
#define P2 4096
#define PK 6144
#define PV 7168

__device__ __forceinline__ unsigned short f2bf(float f) {   // fp32 -> bf16 RNE
  union { float f; unsigned u; } x; x.f = f;
  unsigned r = x.u + 0x7fff + ((x.u >> 16) & 1);
  return (unsigned short)(r >> 16);
}

__device__ __forceinline__ unsigned pkbf(float a, float b) {
#if __has_builtin(__builtin_amdgcn_cvt_pk_bf16_f32)
  typedef __attribute__((ext_vector_type(2))) __bf16 bf16x2_t;
  bf16x2_t v = __builtin_amdgcn_cvt_pk_bf16_f32(a, b);
  return __builtin_bit_cast(unsigned, v);
#else
  return (unsigned)f2bf(a) | ((unsigned)f2bf(b) << 16);
#endif
}

__device__ __forceinline__ float bfu(unsigned short s) {    // bf16 -> fp32
  union { float f; unsigned u; } x; x.u = ((unsigned)s) << 16; return x.f;
}

__device__ __forceinline__ void lds_fence() { asm volatile("s_waitcnt lgkmcnt(0)" ::: "memory"); }
__device__ __forceinline__ float phi(float x) { return x > 0.f ? x + 1.f : __expf(x); }

// XCD-locality swizzle (bijective, NB%8==0): physical blocks round-robin over
// the 8 XCDs, so logical bid = (phys%8)*(NB/8) + phys/8 puts each cloud's 128
// logical blocks on ONE XCD, consistently across k_embed/k_mid/k_last ->
// per-cloud hb (2MB) stays L2-resident between kernels. Pure re-index:
// correctness unaffected if the dispatch->XCD mapping assumption is wrong.
__device__ __forceinline__ int swz_bid() {
  return (blockIdx.x & 7) * (NB >> 3) + (blockIdx.x >> 3);
}

// Feature-major dataflow: D'[out_feat][point] = W^T (A-frag) @ h^T (B-frag).
// B-frag k-order: lane-group q, slot j -> feature (j>=4)*16 + 4q + (j&3).
// D-frag regs {hc0[r]=feat 4q+r, hc1[r]=feat 16+4q+r} pack in-lane (cvt_pk)
// into the next B operand: no LDS transposes on the h path.
__device__ __forceinline__ int perm32(int kp) {
  return ((kp & 4) << 2) | (((kp >> 3) << 2) + (kp & 3));
}

__device__ __forceinline__ bf16x8 bbuild(f32x4 lo, f32x4 hi) {
  union { bf16x8 v; unsigned u[4]; } cv;
  cv.u[0] = pkbf(lo[0], lo[1]); cv.u[1] = pkbf(lo[2], lo[3]);
  cv.u[2] = pkbf(hi[0], hi[1]); cv.u[3] = pkbf(hi[2], hi[3]);
  return cv.v;
}

// ---- weight packing (k_prep, grid-stride): dst[n*32+kp] = W[perm32(kp)][n] ----
__device__ __forceinline__ void stage_a32(unsigned short* dst, const float* __restrict__ W,
                                          int N, int gt, int gs) {
  for (int i = gt; i < 32 * N; i += gs) {
    int n = i >> 5, kp = i & 31;
    dst[i] = f2bf(W[perm32(kp) * N + n]);
  }
}
__device__ __forceinline__ void stage_a64(unsigned short* dst, const float* __restrict__ W,
                                          int gt, int gs) {
  for (int i = gt; i < 64 * 32; i += gs) {
    int n = i >> 6, kp = i & 63;
    int kl = ((kp >> 5) << 5) + perm32(kp & 31);
    dst[i] = f2bf(W[kl * 32 + n]);
  }
}

// cooperative kvm build into LDS: A[e][kp] = same-head ? kv[h][d][e] : 0, d=perm32(kp)
__device__ __forceinline__ void stage_kvm_lds(unsigned short* dst,
                                              const float* __restrict__ kvg, int tid) {
  for (int i = tid; i < 1024; i += BS) {
    int e = i >> 5, kp = i & 31;
    int d = perm32(kp);
    float v = ((d >> 3) == (e >> 3)) ? kvg[(e >> 3) * 64 + (d & 7) * 8 + (e & 7)] : 0.f;
    dst[i] = f2bf(v);
  }
}

// LayerNorm over 32 features, feature-major: in-lane over 8 regs + xor16/xor32.
__device__ __forceinline__ void ln_t(f32x4& a0, f32x4& a1, float4 g0, float4 g1,
                                     float4 b0, float4 b1) {
  float s = a0[0] + a0[1] + a0[2] + a0[3] + a1[0] + a1[1] + a1[2] + a1[3];
  s += __shfl_xor(s, 16); s += __shfl_xor(s, 32);
  float mu = s * (1.f / 32.f);
  float vv = 0.f;
#pragma unroll
  for (int r = 0; r < 4; r++) {
    a0[r] -= mu; a1[r] -= mu;
    vv += a0[r] * a0[r] + a1[r] * a1[r];
  }
  vv += __shfl_xor(vv, 16); vv += __shfl_xor(vv, 32);
  float rstd = rsqrtf(vv * (1.f / 32.f) + EPS_LN);
  a0[0] = a0[0] * rstd * g0.x + b0.x; a0[1] = a0[1] * rstd * g0.y + b0.y;
  a0[2] = a0[2] * rstd * g0.z + b0.z; a0[3] = a0[3] * rstd * g0.w + b0.w;
  a1[0] = a1[0] * rstd * g1.x + b1.x; a1[1] = a1[1] * rstd * g1.y + b1.y;
  a1[2] = a1[2] * rstd * g1.z + b1.z; a1[3] = a1[3] * rstd * g1.w + b1.w;
}

// attention + FFN for one layer; weights from LDS (lw: Q/O/W1/W2 at
// 0/1024/2048/4096), kvm+ksum from LDS; phase A consumes the PRELOADED
// B-frags hBp (bit-identical to bbuild(hc) — cvt_pk of exact bf16 is identity).
__device__ __forceinline__ void layer_core_l(
    f32x4 (&hc0)[4], f32x4 (&hc1)[4], const bf16x8 (&hBp)[4],
    const unsigned short* lw, const unsigned short* kvm, const float* kss,
    int quad, int m,
    const float* __restrict__ bq, const float* __restrict__ bo,
    const float* __restrict__ g1, const float* __restrict__ be1,
    const float* __restrict__ bf1, const float* __restrict__ bf2,
    const float* __restrict__ g2, const float* __restrict__ be2) {
  const int k0 = quad * 8, q4 = quad * 4;
  // ---- phase A: q = phi(h@wq+bq); attn = (q@kvmat)*z; h = LN1(h + attn@wo+bo)
  {
    const bf16x8 wqA0 = *(const bf16x8*)(lw + PQ + m * 32 + k0);
    const bf16x8 wqA1 = *(const bf16x8*)(lw + PQ + (16 + m) * 32 + k0);
    const bf16x8 woA0 = *(const bf16x8*)(lw + PO + m * 32 + k0);
    const bf16x8 woA1 = *(const bf16x8*)(lw + PO + (16 + m) * 32 + k0);
    const bf16x8 kvA0 = *(const bf16x8*)(kvm + m * 32 + k0);
    const bf16x8 kvA1 = *(const bf16x8*)(kvm + (16 + m) * 32 + k0);
    const float4 bq0 = *(const float4*)(bq + q4), bq1 = *(const float4*)(bq + 16 + q4);
    const float4 bo0 = *(const float4*)(bo + q4), bo1 = *(const float4*)(bo + 16 + q4);
    const float4 g10 = *(const float4*)(g1 + q4), g11 = *(const float4*)(g1 + 16 + q4);
    const float4 e10 = *(const float4*)(be1 + q4), e11 = *(const float4*)(be1 + 16 + q4);
    const float4 ks0 = *(const float4*)(kss + q4);
    const float4 ks1 = *(const float4*)(kss + 16 + q4);
#pragma unroll
    for (int mt = 0; mt < 4; mt++) {
      f32x4 q0 = {bq0.x, bq0.y, bq0.z, bq0.w};
      f32x4 q1 = {bq1.x, bq1.y, bq1.z, bq1.w};
      q0 = MFMA(wqA0, hBp[mt], q0);
      q1 = MFMA(wqA1, hBp[mt], q1);
#pragma unroll
      for (int r = 0; r < 4; r++) { q0[r] = phi(q0[r]); q1[r] = phi(q1[r]); }
      bf16x8 qB = bbuild(q0, q1);
      f32x4 zz = {0.f, 0.f, 0.f, 0.f};
      f32x4 at0 = MFMA(kvA0, qB, zz);
      f32x4 at1 = MFMA(kvA1, qB, zz);
      // z: per-head (8-feat) q.ksum; groups q and q^1 hold the two 4-feat halves
      float p0 = q0[0] * ks0.x + q0[1] * ks0.y + q0[2] * ks0.z + q0[3] * ks0.w;
      float p1 = q1[0] * ks1.x + q1[1] * ks1.y + q1[2] * ks1.z + q1[3] * ks1.w;
      p0 += __shfl_xor(p0, 16);
      p1 += __shfl_xor(p1, 16);
      float z0 = 1.f / (p0 + EPS_Z), z1 = 1.f / (p1 + EPS_Z);
      bf16x8 aB;
      {
        union { bf16x8 v; unsigned u[4]; } cv;
        cv.u[0] = pkbf(at0[0] * z0, at0[1] * z0); cv.u[1] = pkbf(at0[2] * z0, at0[3] * z0);
        cv.u[2] = pkbf(at1[0] * z1, at1[1] * z1); cv.u[3] = pkbf(at1[2] * z1, at1[3] * z1);
        aB = cv.v;
      }
      f32x4 h0 = hc0[mt], h1 = hc1[mt];
      h0[0] += bo0.x; h0[1] += bo0.y; h0[2] += bo0.z; h0[3] += bo0.w;
      h1[0] += bo1.x; h1[1] += bo1.y; h1[2] += bo1.z; h1[3] += bo1.w;
      h0 = MFMA(woA0, aB, h0);
      h1 = MFMA(woA1, aB, h1);
      ln_t(h0, h1, g10, g11, e10, e11);
      hc0[mt] = h0; hc1[mt] = h1;
    }
  }
  // ---- phase B: h = LN2(h + relu(h@w1+b1)@w2+b2)
  {
    bf16x8 w1A[4]; float4 b1f[4];
#pragma unroll
    for (int nt = 0; nt < 4; nt++) {
      w1A[nt] = *(const bf16x8*)(lw + P1 + (nt * 16 + m) * 32 + k0);
      b1f[nt] = *(const float4*)(bf1 + nt * 16 + q4);
    }
    const bf16x8 w2L0 = *(const bf16x8*)(lw + P2 + m * 64 + k0);
    const bf16x8 w2H0 = *(const bf16x8*)(lw + P2 + m * 64 + 32 + k0);
    const bf16x8 w2L1 = *(const bf16x8*)(lw + P2 + (16 + m) * 64 + k0);
    const bf16x8 w2H1 = *(const bf16x8*)(lw + P2 + (16 + m) * 64 + 32 + k0);
    const float4 b20 = *(const float4*)(bf2 + q4), b21 = *(const float4*)(bf2 + 16 + q4);
    const float4 g20 = *(const float4*)(g2 + q4), g21 = *(const float4*)(g2 + 16 + q4);
    const float4 e20 = *(const float4*)(be2 + q4), e21 = *(const float4*)(be2 + 16 + q4);
#pragma unroll
    for (int mt = 0; mt < 4; mt++) {
      bf16x8 hB = bbuild(hc0[mt], hc1[mt]);
      f32x4 hd[4];
#pragma unroll
      for (int nt = 0; nt < 4; nt++) {
        f32x4 ini = {b1f[nt].x, b1f[nt].y, b1f[nt].z, b1f[nt].w};
        hd[nt] = MFMA(w1A[nt], hB, ini);
#pragma unroll
        for (int r = 0; r < 4; r++) hd[nt][r] = fmaxf(hd[nt][r], 0.f);
      }
      bf16x8 fL = bbuild(hd[0], hd[1]);
      bf16x8 fH = bbuild(hd[2], hd[3]);
      f32x4 o0 = hc0[mt], o1 = hc1[mt];
      o0[0] += b20.x; o0[1] += b20.y; o0[2] += b20.z; o0[3] += b20.w;
      o1[0] += b21.x; o1[1] += b21.y; o1[2] += b21.z; o1[3] += b21.w;
      o0 = MFMA(w2L0, fL, o0);
      o0 = MFMA(w2H0, fH, o0);
      o1 = MFMA(w2L1, fL, o1);
      o1 = MFMA(w2H1, fH, o1);
      ln_t(o0, o1, g20, g21, e20, e21);
      hc0[mt] = o0; hc1[mt] = o1;
    }
  }
}

// kn = phi(h@wk+bk), vn = h@wv+bv from PRELOADED B-frags; kv += kn^T-outer-vn
// via one LDS transpose per 32-point chunk (points are the contraction dim).
// Stores use cvt_pk pairs (1 pack + 1 shift) instead of 2x scalar f2bf.
__device__ __forceinline__ void kv_stage_l(
    const bf16x8 (&hBp)[4], unsigned short* tw,
    const unsigned short* lwK, const unsigned short* lwV,
    float* blk, int quad, int m,
    const float* __restrict__ bk, const float* __restrict__ bv) {
  const int k0 = quad * 8, q4 = quad * 4;
  unsigned short* Tk = tw;           // [32 feat][40] bf16
  unsigned short* Tv = tw + 1280;    // [32 feat][40] bf16
  const bf16x8 wkA0 = *(const bf16x8*)(lwK + m * 32 + k0);
  const bf16x8 wkA1 = *(const bf16x8*)(lwK + (16 + m) * 32 + k0);
  const bf16x8 wvA0 = *(const bf16x8*)(lwV + m * 32 + k0);
  const bf16x8 wvA1 = *(const bf16x8*)(lwV + (16 + m) * 32 + k0);
  const float4 bk0 = *(const float4*)(bk + q4), bk1 = *(const float4*)(bk + 16 + q4);
  const float4 bv0 = *(const float4*)(bv + q4), bv1 = *(const float4*)(bv + 16 + q4);
  f32x4 accA = {0.f, 0.f, 0.f, 0.f}, accB = {0.f, 0.f, 0.f, 0.f};
  f32x4 ksa0 = {0.f, 0.f, 0.f, 0.f}, ksa1 = {0.f, 0.f, 0.f, 0.f};
#pragma unroll
  for (int ch = 0; ch < 2; ch++) {
#pragma unroll
    for (int mtl = 0; mtl < 2; mtl++) {
      int mt = ch * 2 + mtl;
      f32x4 kn0 = {bk0.x, bk0.y, bk0.z, bk0.w};
      f32x4 kn1 = {bk1.x, bk1.y, bk1.z, bk1.w};
      f32x4 vn0 = {bv0.x, bv0.y, bv0.z, bv0.w};
      f32x4 vn1 = {bv1.x, bv1.y, bv1.z, bv1.w};
      kn0 = MFMA(wkA0, hBp[mt], kn0);
      kn1 = MFMA(wkA1, hBp[mt], kn1);
      vn0 = MFMA(wvA0, hBp[mt], vn0);
      vn1 = MFMA(wvA1, hBp[mt], vn1);
      int cb = mtl * 16 + m;
#pragma unroll
      for (int r = 0; r < 4; r++) {
        kn0[r] = phi(kn0[r]); kn1[r] = phi(kn1[r]);
        ksa0[r] += kn0[r];    ksa1[r] += kn1[r];
        unsigned kk = pkbf(kn0[r], kn1[r]);
        unsigned vv = pkbf(vn0[r], vn1[r]);
        Tk[(q4 + r) * 40 + cb]      = (unsigned short)kk;
        Tk[(16 + q4 + r) * 40 + cb] = (unsigned short)(kk >> 16);
        Tv[(q4 + r) * 40 + cb]      = (unsigned short)vv;
        Tv[(16 + q4 + r) * 40 + cb] = (unsigned short)(vv >> 16);
      }
    }
    lds_fence();
    bf16x8 akL = *(const bf16x8*)(Tk + m * 40 + k0);
    bf16x8 akH = *(const bf16x8*)(Tk + (16 + m) * 40 + k0);
    bf16x8 avL = *(const bf16x8*)(Tv + m * 40 + k0);
    bf16x8 avH = *(const bf16x8*)(Tv + (16 + m) * 40 + k0);
    accA = MFMA(akL, avL, accA);   // d,e in 0..15  (heads 0,1 diag blocks)
    accB = MFMA(akH, avH, accB);   // d,e in 16..31 (heads 2,3 diag blocks)
    lds_fence();
  }
  // ksum[feat]: reduce over the 16 point-lanes
#pragma unroll
  for (int r = 0; r < 4; r++) {
    float v0 = ksa0[r], v1 = ksa1[r];
    v0 += __shfl_xor(v0, 1); v0 += __shfl_xor(v0, 2); v0 += __shfl_xor(v0, 4); v0 += __shfl_xor(v0, 8);
    v1 += __shfl_xor(v1, 1); v1 += __shfl_xor(v1, 2); v1 += __shfl_xor(v1, 4); v1 += __shfl_xor(v1, 8);
    if (m == 0) {
      atomicAdd(&blk[256 + q4 + r], v0);
      atomicAdd(&blk[272 + q4 + r], v1);
    }
  }
  if ((quad >> 1) == (m >> 3)) {   // same-head diagonal blocks only
    int h0 = quad >> 1, h1 = 2 + (quad >> 1), e = m & 7;
#pragma unroll
    for (int r = 0; r < 4; r++) {
      int d = (q4 + r) & 7;
      atomicAdd(&blk[h0 * 64 + d * 8 + e], accA[r]);
      atomicAdd(&blk[h1 * 64 + d * 8 + e], accB[r]);
    }
  }
}

// K0 (64 blocks, grid-stride): pack weights into frag-ready layout + zero kv.
__global__ __launch_bounds__(256) void k_prep(
    const float* __restrict__ w_in, const float* __restrict__ w_pos,
    const float* __restrict__ wq, const float* __restrict__ wk,
    const float* __restrict__ wv, const float* __restrict__ wo,
    const float* __restrict__ w1, const float* __restrict__ w2,
    unsigned short* __restrict__ pw, float* __restrict__ kvbuf) {
  const int gt = blockIdx.x * 256 + threadIdx.x;
  const int gs = gridDim.x * 256;
  for (int i = gt; i < 2 * 16 * KVSZ; i += gs) kvbuf[i] = 0.f;
  for (int i = gt; i < 1024; i += gs) {         // wE identity k-order: cin|pos|0
    int n = i >> 5, k = i & 31;
    float v = k < 16 ? w_in[k * 32 + n] : (k < 19 ? w_pos[(k - 16) * 32 + n] : 0.f);
    pw[PWE + i] = f2bf(v);
  }
  for (int l = 0; l < 2; l++) {
    unsigned short* b = pw + LBASE(l);
    stage_a32(b + PQ, wq + l * 1024, 32, gt, gs);
    stage_a32(b + PO, wo + l * 1024, 32, gt, gs);
    stage_a32(b + P1, w1 + l * 2048, 64, gt, gs);
    stage_a64(b + P2, w2 + l * 2048, gt, gs);
    stage_a32(b + PK, wk + l * 1024, 32, gt, gs);
    stage_a32(b + PV, wv + l * 1024, 32, gt, gs);
  }
}

// K1: embed -> h0 (bf16 B-frag layout in hb, or f32 in hf), layer-0 kv accum.
// x/pos loads issued before LDS staging (T14); XCD-swizzled block index.
template <int H16>
__global__ __launch_bounds__(BS) void k_embed(
    const float* __restrict__ x, const float* __restrict__ pos,
    const float* __restrict__ b_in, const float* __restrict__ b_pos,
    const float* __restrict__ bk, const float* __restrict__ bv,
    const unsigned short* __restrict__ pw, unsigned short* __restrict__ hb,
    float* __restrict__ hf, float* __restrict__ gkv) {
  __shared__ __align__(16) unsigned short lws[3072];
  __shared__ __align__(16) unsigned short tiles[(BS / 64) * 2560];
  __shared__ float blk[KVSZ];
  const int tid = threadIdx.x;
  const int wv_ = tid >> 6, lane = tid & 63, quad = lane >> 4, m = lane & 15;
  unsigned short* tw = tiles + wv_ * 2560;
  const int bid = swz_bid();
  const int cloud = bid >> 7;                   // 128 blocks per cloud
  const int wbase = bid * BS + wv_ * 64;
  const int k0 = quad * 8, q4 = quad * 4;
  // ---- issue x/pos loads early
  float4 xt0[4], xt1[4];
  float pp0[4], pp1[4], pp2[4];
#pragma unroll
  for (int mt = 0; mt < 4; mt++) {
    int p = wbase + mt * 16 + m;
    if (quad < 2) {
      const float4* xp = (const float4*)(x + (size_t)p * 16 + quad * 8);
      xt0[mt] = xp[0]; xt1[mt] = xp[1];
    } else if (quad == 2) {
      const float* pq = pos + (size_t)p * 3;
      pp0[mt] = pq[0]; pp1[mt] = pq[1]; pp2[mt] = pq[2];
    }
  }
  // ---- stage weights (overlaps with x/pos loads in flight)
  for (int j = tid; j < 384; j += BS) {
    int i = j * 8;
    const unsigned short* src = (i < 1024) ? (pw + PWE + i)
                                           : (pw + LBASE(0) + PK + (i - 1024));
    *(bf16x8*)(lws + i) = *(const bf16x8*)src;
  }
  for (int i = tid; i < KVSZ; i += BS) blk[i] = 0.f;
  __syncthreads();
  const bf16x8 weA0 = *(const bf16x8*)(lws + m * 32 + k0);
  const bf16x8 weA1 = *(const bf16x8*)(lws + (16 + m) * 32 + k0);
  float4 bi0, bi1;
  {
    float4 a = *(const float4*)(b_in + q4), b = *(const float4*)(b_pos + q4);
    bi0 = make_float4(a.x + b.x, a.y + b.y, a.z + b.z, a.w + b.w);
    float4 c = *(const float4*)(b_in + 16 + q4), d = *(const float4*)(b_pos + 16 + q4);
    bi1 = make_float4(c.x + d.x, c.y + d.y, c.z + d.z, c.w + d.w);
  }
  bf16x8 fr[4];
#pragma unroll
  for (int mt = 0; mt < 4; mt++) {
    int p = wbase + mt * 16 + m;
    union { bf16x8 v; unsigned u[4]; } xb;
    xb.u[0] = xb.u[1] = xb.u[2] = xb.u[3] = 0;
    if (quad < 2) {
      xb.u[0] = pkbf(xt0[mt].x, xt0[mt].y); xb.u[1] = pkbf(xt0[mt].z, xt0[mt].w);
      xb.u[2] = pkbf(xt1[mt].x, xt1[mt].y); xb.u[3] = pkbf(xt1[mt].z, xt1[mt].w);
    } else if (quad == 2) {
      xb.u[0] = pkbf(pp0[mt], pp1[mt]); xb.u[1] = pkbf(pp2[mt], 0.f);
    }
    f32x4 i0 = {bi0.x, bi0.y, bi0.z, bi0.w};
    f32x4 i1 = {bi1.x, bi1.y, bi1.z, bi1.w};
    f32x4 h0 = MFMA(weA0, xb.v, i0);
    f32x4 h1 = MFMA(weA1, xb.v, i1);
    fr[mt] = bbuild(h0, h1);
    if (H16) {
      *(bf16x8*)(hb + ((size_t)p * 32 + quad * 8)) = fr[mt];
    } else {
      float* hp = hf + (size_t)p * 32;
      *(float4*)(hp + q4)      = make_float4(h0[0], h0[1], h0[2], h0[3]);
      *(float4*)(hp + 16 + q4) = make_float4(h1[0], h1[1], h1[2], h1[3]);
    }
  }
  kv_stage_l(fr, tw, lws + 1024, lws + 2048, blk, quad, m, bk, bv);
  __syncthreads();
  float* g = gkv + cloud * KVSZ;
  for (int i = tid; i < KVSZ; i += BS) atomicAdd(&g[i], blk[i]);
}

// K2: layer-0 attn+FFN (in place on h), layer-1 kn/vn -> kv accum.
// hb frag loads issued before LDS staging; same swizzle as k_embed.
template <int H16>
__global__ __launch_bounds__(BS) void k_mid(
    const float* __restrict__ bq, const float* __restrict__ bo,
    const float* __restrict__ g1, const float* __restrict__ be1,
    const float* __restrict__ bf1, const float* __restrict__ bf2,
    const float* __restrict__ g2, const float* __restrict__ be2,
    const float* __restrict__ bkn, const float* __restrict__ bvn,
    const unsigned short* __restrict__ pw, const float* __restrict__ kv_in,
    float* __restrict__ gkv_out, unsigned short* __restrict__ hb,
    float* __restrict__ hf) {
  __shared__ __align__(16) unsigned short lws[8192];
  __shared__ __align__(16) unsigned short kvm[1024];
  __shared__ __align__(16) float kss[32];
  __shared__ __align__(16) unsigned short tiles[(BS / 64) * 2560];
  __shared__ float blk[KVSZ];
  const int tid = threadIdx.x;
  const int wv_ = tid >> 6, lane = tid & 63, quad = lane >> 4, m = lane & 15;
  unsigned short* tw = tiles + wv_ * 2560;
  const int bid = swz_bid();
  const int cloud = bid >> 7;
  const int wbase = bid * BS + wv_ * 64;
  const int q4 = quad * 4;
  const float* kvg = kv_in + cloud * KVSZ;
  // ---- issue h loads early
  bf16x8 fr[4];
  if (H16) {
#pragma unroll
    for (int mt = 0; mt < 4; mt++) {
      int p = wbase + mt * 16 + m;
      fr[mt] = *(const bf16x8*)(hb + ((size_t)p * 32 + quad * 8));
    }
  }
  // ---- stage weights + kvm + ksum (h loads in flight)
  for (int j = tid; j < 1024; j += BS) {
    int i = j * 8;
    const unsigned short* src = (i < 6144) ? (pw + LBASE(0) + i)
                                           : (pw + LBASE(1) + PK + (i - 6144));
    *(bf16x8*)(lws + i) = *(const bf16x8*)src;
  }
  stage_kvm_lds(kvm, kvg, tid);
  if (tid < 32) kss[tid] = kvg[256 + tid];
  for (int i = tid; i < KVSZ; i += BS) blk[i] = 0.f;
  __syncthreads();
  f32x4 hc0[4], hc1[4];
#pragma unroll
  for (int mt = 0; mt < 4; mt++) {
    if (H16) {
#pragma unroll
      for (int r = 0; r < 4; r++) {
        hc0[mt][r] = bfu((unsigned short)fr[mt][r]);
        hc1[mt][r] = bfu((unsigned short)fr[mt][4 + r]);
      }
    } else {
      int p = wbase + mt * 16 + m;
      const float* hp = hf + (size_t)p * 32;
      float4 lo = *(const float4*)(hp + q4);
      float4 hi = *(const float4*)(hp + 16 + q4);
      hc0[mt][0] = lo.x; hc0[mt][1] = lo.y; hc0[mt][2] = lo.z; hc0[mt][3] = lo.w;
      hc1[mt][0] = hi.x; hc1[mt][1] = hi.y; hc1[mt][2] = hi.z; hc1[mt][3] = hi.w;
      fr[mt] = bbuild(hc0[mt], hc1[mt]);
    }
  }
  layer_core_l(hc0, hc1, fr, lws, kvm, kss, quad, m,
               bq, bo, g1, be1, bf1, bf2, g2, be2);
#pragma unroll
  for (int mt = 0; mt < 4; mt++) {
    int p = wbase + mt * 16 + m;
    fr[mt] = bbuild(hc0[mt], hc1[mt]);
    if (H16) {
      *(bf16x8*)(hb + ((size_t)p * 32 + quad * 8)) = fr[mt];
    } else {
      float* hp = hf + (size_t)p * 32;
      *(float4*)(hp + q4)      = make_float4(hc0[mt][0], hc0[mt][1], hc0[mt][2], hc0[mt][3]);
      *(float4*)(hp + 16 + q4) = make_float4(hc1[mt][0], hc1[mt][1], hc1[mt][2], hc1[mt][3]);
    }
  }
  kv_stage_l(fr, tw, lws + 6144, lws + 7168, blk, quad, m, bkn, bvn);
  __syncthreads();
  float* g = gkv_out + cloud * KVSZ;
  for (int i = tid; i < KVSZ; i += BS) atomicAdd(&g[i], blk[i]);
}

// K3: layer-1 attn+FFN -> final fp32 output. Early hb loads; same swizzle.
template <int H16>
__global__ __launch_bounds__(BS) void k_last(
    const float* __restrict__ bq, const float* __restrict__ bo,
    const float* __restrict__ g1, const float* __restrict__ be1,
    const float* __restrict__ bf1, const float* __restrict__ bf2,
    const float* __restrict__ g2, const float* __restrict__ be2,
    const unsigned short* __restrict__ pw, const float* __restrict__ kv_in,
    const unsigned short* __restrict__ hb, float* __restrict__ out) {
  __shared__ __align__(16) unsigned short lws[6144];
  __shared__ __align__(16) unsigned short kvm[1024];
  __shared__ __align__(16) float kss[32];
  const int tid = threadIdx.x;
  const int wv_ = tid >> 6, lane = tid & 63, quad = lane >> 4, m = lane & 15;
  const int bid = swz_bid();
  const int cloud = bid >> 7;
  const int wbase = bid * BS + wv_ * 64;
  const int q4 = quad * 4;
  const float* kvg = kv_in + cloud * KVSZ;
  bf16x8 fr[4];
  if (H16) {
#pragma unroll
    for (int mt = 0; mt < 4; mt++) {
      int p = wbase + mt * 16 + m;
      fr[mt] = *(const bf16x8*)(hb + ((size_t)p * 32 + quad * 8));
    }
  }
  for (int j = tid; j < 768; j += BS)
    *(bf16x8*)(lws + j * 8) = *(const bf16x8*)(pw + LBASE(1) + j * 8);
  stage_kvm_lds(kvm, kvg, tid);
  if (tid < 32) kss[tid] = kvg[256 + tid];
  __syncthreads();
  f32x4 hc0[4], hc1[4];
#pragma unroll
  for (int mt = 0; mt < 4; mt++) {
    if (H16) {
#pragma unroll
      for (int r = 0; r < 4; r++) {
        hc0[mt][r] = bfu((unsigned short)fr[mt][r]);
        hc1[mt][r] = bfu((unsigned short)fr[mt][4 + r]);
      }
    } else {
      int p = wbase + mt * 16 + m;
      const float* hp = out + (size_t)p * 32;
      float4 lo = *(const float4*)(hp + q4);
      float4 hi = *(const float4*)(hp + 16 + q4);
      hc0[mt][0] = lo.x; hc0[mt][1] = lo.y; hc0[mt][2] = lo.z; hc0[mt][3] = lo.w;
      hc1[mt][0] = hi.x; hc1[mt][1] = hi.y; hc1[mt][2] = hi.z; hc1[mt][3] = hi.w;
      fr[mt] = bbuild(hc0[mt], hc1[mt]);
    }
  }
  layer_core_l(hc0, hc1, fr, lws, kvm, kss, quad, m,
               bq, bo, g1, be1, bf1, bf2, g2, be2);
#pragma unroll
  for (int mt = 0; mt < 4; mt++) {
    int p = wbase + mt * 16 + m;
    float* hp = out + (size_t)p * 32;
    *(float4*)(hp + q4)      = make_float4(hc0[mt][0], hc0[mt][1], hc0[mt][2], hc0[mt][3]);
    *(float4*)(hp + 16 + q4) = make_float4(hc1[mt][0], hc1[mt][1], hc1[mt][2], hc1[mt][3]);
  }
}

extern "C" void kernel_launch(void* const* d_in, const int* in_sizes, int n_in,
                              void* d_out, int out_size, void* d_ws, size_t ws_size,
                              hipStream_t stream) {
  (void)in_sizes; (void)n_in; (void)out_size;
  const float* x     = (const float*)d_in[0];
  const float* pos   = (const float*)d_in[1];
  // d_in[2] = batch (arange // N_PER): identity mapping, unused
  const float* w_in  = (const float*)d_in[3];
  const float* b_in  = (const float*)d_in[4];
  const float* w_pos = (const float*)d_in[5];
  const float* b_pos = (const float*)d_in[6];
  const float* wq  = (const float*)d_in[7];
  const float* bq  = (const float*)d_in[8];
  const float* wk  = (const float*)d_in[9];
  const float* bk  = (const float*)d_in[10];
  const float* wv  = (const float*)d_in[11];
  const float* bv  = (const float*)d_in[12];
  const float* wo  = (const float*)d_in[13];
  const float* bo  = (const float*)d_in[14];
  const float* g1  = (const float*)d_in[15];
  const float* be1 = (const float*)d_in[16];
  const float* w1  = (const float*)d_in[17];
  const float* bf1 = (const float*)d_in[18];
  const float* w2  = (const float*)d_in[19];
  const float* bf2 = (const float*)d_in[20];
  const float* g2  = (const float*)d_in[21];
  const float* be2 = (const float*)d_in[22];
  float* out = (float*)d_out;
  // workspace layout: [0,36864) kv (2 layers x 16 clouds x 288 f32);
  // [40960, 75776) packed weights (17408 bf16); [131072, +33.5MB) bf16 h.
  float* kvbuf = (float*)d_ws;
  unsigned short* pw = (unsigned short*)((char*)d_ws + 40960);
  unsigned short* hb = (unsigned short*)((char*)d_ws + 131072);
  const size_t need = 131072ull + 524288ull * 32ull * 2ull;
  const bool h16 = ws_size >= need;

  k_prep<<<dim3(64), dim3(256), 0, stream>>>(w_in, w_pos, wq, wk, wv, wo, w1, w2,
                                             pw, kvbuf);
  dim3 grid(NB), block(BS);
  if (h16) {
    k_embed<1><<<grid, block, 0, stream>>>(x, pos, b_in, b_pos, bk, bv, pw, hb, out, kvbuf);
    k_mid<1><<<grid, block, 0, stream>>>(bq, bo, g1, be1, bf1, bf2, g2, be2,
                                         bk + 32, bv + 32, pw, kvbuf,
                                         kvbuf + 16 * KVSZ, hb, out);
    k_last<1><<<grid, block, 0, stream>>>(bq + 32, bo + 32, g1 + 32, be1 + 32,
                                          bf1 + 64, bf2 + 32, g2 + 32, be2 + 32,
                                          pw, kvbuf + 16 * KVSZ, hb, out);
  } else {
    k_embed<0><<<grid, block, 0, stream>>>(x, pos, b_in, b_pos, bk, bv, pw, hb, out, kvbuf);
    k_mid<0><<<grid, block, 0, stream>>>(bq, bo, g1, be1, bf1, bf2, g2, be2,
                                         bk + 32, bv + 32, pw, kvbuf,
                                         kvbuf + 16 * KVSZ, hb, out);
    k_last<0><<<grid, block, 0, stream>>>(bq + 32, bo + 32, g1 + 32, be1 + 32,
                                          bf1 + 64, bf2 + 32, g2 + 32, be2 + 32,
                                          pw, kvbuf + 16 * KVSZ, hb, out);
  }
}